// Round 4
// baseline (95.128 us; speedup 1.0000x reference)
//
#include <hip/hip_runtime.h>

#define NSAMP 64
#define PER_SAMPLE (512 * 512)                 // 262144 elements per sample
#define BLOCKS_PER_SAMPLE 32
#define NBLOCKS (NSAMP * BLOCKS_PER_SAMPLE)    // 2048 blocks
#define THREADS 256
#define TOPK 42
#define LOG2_CLAMP -144.26950408889634f        // -100 / ln(2)
#define LN2F 0.69314718055994531f

// Single fused kernel:
//  phase 1: each block computes a deterministic partial BCE sum (log2 domain)
//           over its contiguous 8192-element chunk of one sample.
//  phase 2: block writes partial (agent-scope), bumps a done-counter; the
//           LAST block gathers all partials (coalesced, transposed layout),
//           forms per-sample means, rank-selects top-42, writes the scalar.
__global__ __launch_bounds__(THREADS) void ohem_fused(
    const float* __restrict__ preds,
    const float* __restrict__ targets,
    float* __restrict__ partials,          // NBLOCKS floats, layout [chunk][sample]
    unsigned int* __restrict__ counter,    // zeroed on-stream before launch
    float* __restrict__ out) {
    const int vec_per_sample = PER_SAMPLE / 4;                      // 65536
    const int vec_per_block  = vec_per_sample / BLOCKS_PER_SAMPLE;  // 2048 float4
    const int sample = blockIdx.x >> 5;          // /32
    const int chunk  = blockIdx.x & 31;          // %32
    const size_t base = (size_t)sample * vec_per_sample + (size_t)chunk * vec_per_block;

    const float4* __restrict__ p4 = (const float4*)preds;
    const float4* __restrict__ t4 = (const float4*)targets;

    // acc holds +(t*log2(p) + (1-t)*log2(1-p)); negate & scale by ln2 at end.
    float acc = 0.0f;
    #pragma unroll
    for (int b = 0; b < 2; ++b) {
        float4 p[4], t[4];
        #pragma unroll
        for (int j = 0; j < 4; ++j) {
            const int i = (b * 4 + j) * THREADS + threadIdx.x;
            p[j] = p4[base + i];
            t[j] = t4[base + i];
        }
        // Pin all 8 global_load_dwordx4 ABOVE any consumer: forces 8 loads
        // in flight per wave (the compiler otherwise re-serializes to save
        // VGPRs -- R3 showed VGPR_Count=24).
        __builtin_amdgcn_sched_barrier(0);
        #pragma unroll
        for (int j = 0; j < 4; ++j) {
            {
                float lp = fmaxf(__log2f(p[j].x),        LOG2_CLAMP);
                float l1 = fmaxf(__log2f(1.0f - p[j].x), LOG2_CLAMP);
                acc += l1;  acc = fmaf(t[j].x, lp - l1, acc);
            }
            {
                float lp = fmaxf(__log2f(p[j].y),        LOG2_CLAMP);
                float l1 = fmaxf(__log2f(1.0f - p[j].y), LOG2_CLAMP);
                acc += l1;  acc = fmaf(t[j].y, lp - l1, acc);
            }
            {
                float lp = fmaxf(__log2f(p[j].z),        LOG2_CLAMP);
                float l1 = fmaxf(__log2f(1.0f - p[j].z), LOG2_CLAMP);
                acc += l1;  acc = fmaf(t[j].z, lp - l1, acc);
            }
            {
                float lp = fmaxf(__log2f(p[j].w),        LOG2_CLAMP);
                float l1 = fmaxf(__log2f(1.0f - p[j].w), LOG2_CLAMP);
                acc += l1;  acc = fmaf(t[j].w, lp - l1, acc);
            }
        }
    }

    // wave (64-lane) butterfly reduction
    #pragma unroll
    for (int off = 32; off > 0; off >>= 1) acc += __shfl_down(acc, off, 64);

    __shared__ float smem[THREADS / 64];
    __shared__ int is_last;
    const int lane = threadIdx.x & 63;
    const int wid  = threadIdx.x >> 6;
    if (lane == 0) smem[wid] = acc;
    __syncthreads();
    if (threadIdx.x == 0) {
        float tot = 0.0f;
        #pragma unroll
        for (int w = 0; w < THREADS / 64; ++w) tot += smem[w];
        // Transposed layout: [chunk][sample] so the final gather is coalesced.
        __hip_atomic_store(&partials[chunk * NSAMP + sample], -tot * LN2F,
                           __ATOMIC_RELAXED, __HIP_MEMORY_SCOPE_AGENT);
        unsigned int old = __hip_atomic_fetch_add(counter, 1u,
                           __ATOMIC_ACQ_REL, __HIP_MEMORY_SCOPE_AGENT);
        is_last = (old == NBLOCKS - 1);
    }
    __syncthreads();

    if (is_last) {
        __shared__ float vals[NSAMP];
        const int tid = threadIdx.x;
        if (tid < NSAMP) {
            float s = 0.0f;
            #pragma unroll
            for (int c = 0; c < BLOCKS_PER_SAMPLE; ++c)
                s += __hip_atomic_load(&partials[c * NSAMP + tid],
                                       __ATOMIC_RELAXED, __HIP_MEMORY_SCOPE_AGENT);
            vals[tid] = s * (1.0f / (float)PER_SAMPLE);
        }
        __syncthreads();
        if (tid < NSAMP) {
            const float loss = vals[tid];
            // Descending stable rank: exactly TOPK entries get rank < TOPK.
            int rank = 0;
            for (int j = 0; j < NSAMP; ++j) {
                float v = vals[j];
                rank += (v > loss) || (v == loss && j < tid);
            }
            float contrib = (rank < TOPK) ? loss : 0.0f;
            #pragma unroll
            for (int off = 32; off > 0; off >>= 1)
                contrib += __shfl_down(contrib, off, 64);
            if (tid == 0) out[0] = contrib * (1.0f / (float)TOPK);
        }
    }
}

extern "C" void kernel_launch(void* const* d_in, const int* in_sizes, int n_in,
                              void* d_out, int out_size, void* d_ws, size_t ws_size,
                              hipStream_t stream) {
    const float* preds   = (const float*)d_in[0];
    const float* targets = (const float*)d_in[1];
    float* out      = (float*)d_out;
    float* partials = (float*)d_ws;                       // NBLOCKS floats = 8 KB
    unsigned int* counter = (unsigned int*)((char*)d_ws + NBLOCKS * sizeof(float));

    hipMemsetAsync(counter, 0, sizeof(unsigned int), stream);
    ohem_fused<<<NBLOCKS, THREADS, 0, stream>>>(preds, targets, partials, counter, out);
}

// Round 5
// 27.211 us; speedup vs baseline: 3.4960x; 3.4960x over previous
//
#include <hip/hip_runtime.h>

#define NSAMP 64
#define PER_SAMPLE (512 * 512)                 // 262144 elements per sample
#define BLOCKS_PER_SAMPLE 32
#define NBLOCKS (NSAMP * BLOCKS_PER_SAMPLE)    // 2048 blocks
#define THREADS 256
#define TOPK 42
#define LOG2_CLAMP -144.26950408889634f        // -100 / ln(2)
#define LN2F 0.69314718055994531f

// Issue a 16B load the compiler cannot re-serialize. Completion is NOT
// tracked by the compiler -- caller must s_waitcnt vmcnt(N) before use.
__device__ __forceinline__ void issue_load(float4& dst, const float4* addr) {
    asm volatile("global_load_dwordx4 %0, %1, off" : "=v"(dst) : "v"(addr));
}

// Kernel 1: per-block partial BCE sums (log2 domain), forced 16-deep MLP.
// Each block owns a contiguous 8192-element chunk of one sample.
__global__ __launch_bounds__(THREADS) void bce_partial(
    const float* __restrict__ preds,
    const float* __restrict__ targets,
    float* __restrict__ partials) {
    const int vec_per_sample = PER_SAMPLE / 4;                      // 65536
    const int vec_per_block  = vec_per_sample / BLOCKS_PER_SAMPLE;  // 2048 float4
    const int sample = blockIdx.x >> 5;          // /32
    const int chunk  = blockIdx.x & 31;          // %32
    const size_t base = (size_t)sample * vec_per_sample + (size_t)chunk * vec_per_block;

    const float4* __restrict__ pp = (const float4*)preds   + base + threadIdx.x;
    const float4* __restrict__ tt = (const float4*)targets + base + threadIdx.x;

    float4 p[8], t[8];
    // Issue all 16 loads back-to-back: 16 outstanding dwordx4 per lane.
    #pragma unroll
    for (int j = 0; j < 8; ++j) {
        issue_load(p[j], pp + j * THREADS);
        issue_load(t[j], tt + j * THREADS);
    }

    float acc = 0.0f;   // +(t*log2 p + (1-t)*log2(1-p)); negate*ln2 at end

    // First 8 loads (pairs 0..3) complete when <=8 remain outstanding.
    asm volatile("s_waitcnt vmcnt(8)" ::: "memory");
    __builtin_amdgcn_sched_barrier(0);
    #pragma unroll
    for (int j = 0; j < 4; ++j) {
        float lpx = fmaxf(__log2f(p[j].x), LOG2_CLAMP), l1x = fmaxf(__log2f(1.0f - p[j].x), LOG2_CLAMP);
        float lpy = fmaxf(__log2f(p[j].y), LOG2_CLAMP), l1y = fmaxf(__log2f(1.0f - p[j].y), LOG2_CLAMP);
        float lpz = fmaxf(__log2f(p[j].z), LOG2_CLAMP), l1z = fmaxf(__log2f(1.0f - p[j].z), LOG2_CLAMP);
        float lpw = fmaxf(__log2f(p[j].w), LOG2_CLAMP), l1w = fmaxf(__log2f(1.0f - p[j].w), LOG2_CLAMP);
        acc += l1x;  acc = fmaf(t[j].x, lpx - l1x, acc);
        acc += l1y;  acc = fmaf(t[j].y, lpy - l1y, acc);
        acc += l1z;  acc = fmaf(t[j].z, lpz - l1z, acc);
        acc += l1w;  acc = fmaf(t[j].w, lpw - l1w, acc);
    }

    asm volatile("s_waitcnt vmcnt(0)" ::: "memory");
    __builtin_amdgcn_sched_barrier(0);
    #pragma unroll
    for (int j = 4; j < 8; ++j) {
        float lpx = fmaxf(__log2f(p[j].x), LOG2_CLAMP), l1x = fmaxf(__log2f(1.0f - p[j].x), LOG2_CLAMP);
        float lpy = fmaxf(__log2f(p[j].y), LOG2_CLAMP), l1y = fmaxf(__log2f(1.0f - p[j].y), LOG2_CLAMP);
        float lpz = fmaxf(__log2f(p[j].z), LOG2_CLAMP), l1z = fmaxf(__log2f(1.0f - p[j].z), LOG2_CLAMP);
        float lpw = fmaxf(__log2f(p[j].w), LOG2_CLAMP), l1w = fmaxf(__log2f(1.0f - p[j].w), LOG2_CLAMP);
        acc += l1x;  acc = fmaf(t[j].x, lpx - l1x, acc);
        acc += l1y;  acc = fmaf(t[j].y, lpy - l1y, acc);
        acc += l1z;  acc = fmaf(t[j].z, lpz - l1z, acc);
        acc += l1w;  acc = fmaf(t[j].w, lpw - l1w, acc);
    }

    // wave (64-lane) butterfly reduction
    #pragma unroll
    for (int off = 32; off > 0; off >>= 1) acc += __shfl_down(acc, off, 64);

    __shared__ float smem[THREADS / 64];
    const int lane = threadIdx.x & 63;
    const int wid  = threadIdx.x >> 6;
    if (lane == 0) smem[wid] = acc;
    __syncthreads();
    if (threadIdx.x == 0) {
        float tot = 0.0f;
        #pragma unroll
        for (int w = 0; w < THREADS / 64; ++w) tot += smem[w];
        partials[blockIdx.x] = -tot * LN2F;   // back to natural-log domain
    }
}

// Kernel 2: one 64-thread block. Vectorized gather of 32 partials/sample,
// per-sample mean; stable O(64^2) rank to pick the 42 largest; mean.
__global__ __launch_bounds__(64) void topk_mean(
    const float* __restrict__ partials,
    float* __restrict__ out) {
    const int tid = threadIdx.x;  // one sample per thread
    const float4* __restrict__ pp4 = (const float4*)partials;

    float4 a[8];
    #pragma unroll
    for (int j = 0; j < 8; ++j) a[j] = pp4[tid * 8 + j];   // 32 floats/sample
    float s = 0.0f;
    #pragma unroll
    for (int j = 0; j < 8; ++j) s += a[j].x + a[j].y + a[j].z + a[j].w;
    const float loss = s * (1.0f / (float)PER_SAMPLE);

    __shared__ float vals[NSAMP];
    vals[tid] = loss;
    __syncthreads();

    // Descending stable rank: exactly TOPK entries get rank < TOPK.
    int rank = 0;
    for (int j = 0; j < NSAMP; ++j) {
        float v = vals[j];
        rank += (v > loss) || (v == loss && j < tid);
    }
    float contrib = (rank < TOPK) ? loss : 0.0f;

    #pragma unroll
    for (int off = 32; off > 0; off >>= 1) contrib += __shfl_down(contrib, off, 64);

    if (tid == 0) out[0] = contrib * (1.0f / (float)TOPK);
}

extern "C" void kernel_launch(void* const* d_in, const int* in_sizes, int n_in,
                              void* d_out, int out_size, void* d_ws, size_t ws_size,
                              hipStream_t stream) {
    const float* preds   = (const float*)d_in[0];
    const float* targets = (const float*)d_in[1];
    float* out      = (float*)d_out;
    float* partials = (float*)d_ws;   // NBLOCKS floats = 8 KB

    bce_partial<<<NBLOCKS, THREADS, 0, stream>>>(preds, targets, partials);
    topk_mean<<<1, 64, 0, stream>>>(partials, out);
}